// Round 3
// baseline (796.034 us; speedup 1.0000x reference)
//
#include <hip/hip_runtime.h>
#include <stdint.h>

// out = dequant( int8(lhs*ls) @ int8(rhs*rs) ) / (ls*rs), 4096^3, fp32 in/out.
// ls = 127 / max(amax|lhs|, 1e-12). Int core is bit-exact vs numpy (RNE quant).
//
// Workspace: [0,16Mi) qA int8 MxK ; [16Mi,32Mi) qBT int8 NxK ; then 2x u32 amax bits.
//
// GEMM v4: 256x256 tile, 8 waves (2Mx4N), BK=64, ring-4 LDS (128 KiB),
// REGISTER fragment double-buffer (window t MFMAs tile t from regs loaded in
// window t-1 while ds-reading tile t+1) + wave-group order swap (waves 0-3
// MFMA-then-read, waves 4-7 read-then-MFMA; one of each per SIMD) so the LDS
// and MFMA pipes overlap instead of serializing in lockstep. Counted
// vmcnt(4): stage(t+3) issued in window t, tile t+2 retired at end of window
// t, read during window t+1 -- loads stay 2 windows in flight, never drained.
// XCD-aware block swizzle: XCD k owns M-rows {2k,2k+1} -> A-panels L2-resident.

#define NROW 4096
#define NELEM (4096 * 4096)

typedef __attribute__((ext_vector_type(4))) int int32x4;
typedef const __attribute__((address_space(1))) int8_t* gptr1_t;
typedef __attribute__((address_space(3))) int8_t* lptr3_t;

__global__ void absmax_both_kernel(const float* __restrict__ lhs,
                                   const float* __restrict__ rhs,
                                   unsigned* __restrict__ amax) {
    __shared__ float red[4];
    const int t = blockIdx.x & 1;
    const float4* x4 = (const float4*)(t ? rhs : lhs);
    const int bid = blockIdx.x >> 1;
    const int stride = (gridDim.x >> 1) * blockDim.x;  // 262144
    int i = bid * blockDim.x + threadIdx.x;
    float m0 = 0.0f, m1 = 0.0f, m2 = 0.0f, m3 = 0.0f;
    for (; i + 3 * stride < NELEM / 4; i += 4 * stride) {
        float4 a = x4[i];
        float4 b = x4[i + stride];
        float4 c = x4[i + 2 * stride];
        float4 d = x4[i + 3 * stride];
        m0 = fmaxf(m0, fmaxf(fmaxf(fabsf(a.x), fabsf(a.y)),
                             fmaxf(fabsf(a.z), fabsf(a.w))));
        m1 = fmaxf(m1, fmaxf(fmaxf(fabsf(b.x), fabsf(b.y)),
                             fmaxf(fabsf(b.z), fabsf(b.w))));
        m2 = fmaxf(m2, fmaxf(fmaxf(fabsf(c.x), fabsf(c.y)),
                             fmaxf(fabsf(c.z), fabsf(c.w))));
        m3 = fmaxf(m3, fmaxf(fmaxf(fabsf(d.x), fabsf(d.y)),
                             fmaxf(fabsf(d.z), fabsf(d.w))));
    }
    for (; i < NELEM / 4; i += stride) {
        float4 a = x4[i];
        m0 = fmaxf(m0, fmaxf(fmaxf(fabsf(a.x), fabsf(a.y)),
                             fmaxf(fabsf(a.z), fabsf(a.w))));
    }
    float m = fmaxf(fmaxf(m0, m1), fmaxf(m2, m3));
    for (int off = 32; off > 0; off >>= 1)
        m = fmaxf(m, __shfl_down(m, off, 64));
    const int lane = threadIdx.x & 63, wave = threadIdx.x >> 6;
    if (lane == 0) red[wave] = m;
    __syncthreads();
    if (threadIdx.x == 0) {
        float b = fmaxf(fmaxf(red[0], red[1]), fmaxf(red[2], red[3]));
        atomicMax(amax + t, __float_as_uint(b));  // |x|>=0: bits monotone as uint
    }
}

__device__ __forceinline__ int q8(float v, float s) {
    int r = __float2int_rn(v * s);  // RNE, matches jnp.round
    r = r < -127 ? -127 : r;
    r = r > 127 ? 127 : r;
    return r;
}

__global__ void quant_kernel(const float* __restrict__ lhs,
                             const float* __restrict__ rhs,
                             int8_t* __restrict__ qA, int8_t* __restrict__ qT,
                             const unsigned* __restrict__ amax) {
    __shared__ int8_t sm[64][68];
    if (blockIdx.x < 16384) {
        const float s = 127.0f / fmaxf(__uint_as_float(amax[0]), 1e-12f);
        const int i = blockIdx.x * blockDim.x + threadIdx.x;
        float4 v = ((const float4*)lhs)[i];
        int b0 = q8(v.x, s), b1 = q8(v.y, s), b2 = q8(v.z, s), b3 = q8(v.w, s);
        ((int*)qA)[i] = (b0 & 0xff) | ((b1 & 0xff) << 8) | ((b2 & 0xff) << 16)
                      | ((b3 & 0xff) << 24);
    } else {
        const float s = 127.0f / fmaxf(__uint_as_float(amax[1]), 1e-12f);
        const int b = blockIdx.x - 16384;
        const int n0 = (b & 63) * 64, k0 = (b >> 6) * 64;
        const int rl = threadIdx.x >> 4;   // k row within 16-row slab
        const int nq = threadIdx.x & 15;   // float4 column
        for (int r = 0; r < 4; ++r) {
            const int kl = r * 16 + rl;
            float4 v = *(const float4*)(rhs + (size_t)(k0 + kl) * NROW + n0 + nq * 4);
            sm[nq * 4 + 0][kl] = (int8_t)q8(v.x, s);
            sm[nq * 4 + 1][kl] = (int8_t)q8(v.y, s);
            sm[nq * 4 + 2][kl] = (int8_t)q8(v.z, s);
            sm[nq * 4 + 3][kl] = (int8_t)q8(v.w, s);
        }
        __syncthreads();
        const int nl = threadIdx.x >> 2;
        const int kq = threadIdx.x & 3;
        int4 w;
        w.x = *(const int*)&sm[nl][kq * 16 + 0];
        w.y = *(const int*)&sm[nl][kq * 16 + 4];
        w.z = *(const int*)&sm[nl][kq * 16 + 8];
        w.w = *(const int*)&sm[nl][kq * 16 + 12];
        *(int4*)(qT + (size_t)(n0 + nl) * NROW + k0 + kq * 16) = w;
    }
}

struct Frags {
    int32x4 a[8];
    int32x4 b[4];
};

__device__ __forceinline__ void mfma_all(int32x4 (&acc)[8][4], const Frags& f) {
    __builtin_amdgcn_s_setprio(1);
#pragma unroll
    for (int mi = 0; mi < 8; ++mi)
#pragma unroll
        for (int ni = 0; ni < 4; ++ni)
            acc[mi][ni] = __builtin_amdgcn_mfma_i32_16x16x64_i8(
                f.a[mi], f.b[ni], acc[mi][ni], 0, 0, 0);
    __builtin_amdgcn_s_setprio(0);
}

__device__ __forceinline__ void read_frags(Frags& f, const int8_t* a,
                                           const int8_t* b, int aoff,
                                           int boff) {
#pragma unroll
    for (int mi = 0; mi < 8; ++mi)
        f.a[mi] = *(const int32x4*)(a + aoff + mi * 1024);
#pragma unroll
    for (int ni = 0; ni < 4; ++ni)
        f.b[ni] = *(const int32x4*)(b + boff + ni * 1024);
}

// One window: optionally stage tile t+3 (4 global_load_lds), MFMA tile t from
// fc (regs), ds-read tile t+1 frags into fn. Group order swap: mfma_first
// waves keep the MFMA pipe busy while the others feed the LDS pipe, then swap.
// VM: 4 = counted retire (steady), 0 = drain (window 61), -1 = none.
template <bool DO_STAGE, int VM>
__device__ __forceinline__ void window(
    int32x4 (&acc)[8][4], Frags& fc, Frags& fn, const int8_t* rdA,
    const int8_t* rdB, int aoff, int boff, bool mfma_first, gptr1_t pA0,
    gptr1_t pA1, gptr1_t pB0, gptr1_t pB1, lptr3_t dA0, lptr3_t dA1,
    lptr3_t dB0, lptr3_t dB1) {
    if (DO_STAGE) {
        __builtin_amdgcn_global_load_lds(pA0, dA0, 16, 0, 0);
        __builtin_amdgcn_global_load_lds(pA1, dA1, 16, 0, 0);
        __builtin_amdgcn_global_load_lds(pB0, dB0, 16, 0, 0);
        __builtin_amdgcn_global_load_lds(pB1, dB1, 16, 0, 0);
    }
    if (mfma_first) {
        mfma_all(acc, fc);
        __builtin_amdgcn_sched_barrier(0);
        read_frags(fn, rdA, rdB, aoff, boff);
    } else {
        read_frags(fn, rdA, rdB, aoff, boff);
        __builtin_amdgcn_sched_barrier(0);
        mfma_all(acc, fc);
    }
    if (VM == 4) asm volatile("s_waitcnt vmcnt(4)" ::: "memory");
    if (VM == 0) asm volatile("s_waitcnt vmcnt(0)" ::: "memory");
    __builtin_amdgcn_sched_barrier(0);
    __builtin_amdgcn_s_barrier();
}

__global__ __launch_bounds__(512, 2) void gemm_i8_kernel(
    const int8_t* __restrict__ qA, const int8_t* __restrict__ qBT,
    float* __restrict__ out, const unsigned* __restrict__ amax) {
    __shared__ __align__(16) int8_t sA[4][256 * 64];
    __shared__ __align__(16) int8_t sB[4][256 * 64];

    const int tid = threadIdx.x;
    const int lane = tid & 63;
    const int wave = tid >> 6;      // 0..7
    const int wm = wave >> 2;       // 0..1 : 128-row sub-tile
    const int wn = wave & 3;        // 0..3 : 64-col sub-tile
    const bool mfma_first = wave < 4;  // one of each group per SIMD

    // XCD-aware bijective swizzle (grid 256, 256%8==0): XCD k (= original
    // linear id % 8) gets swz ids [32k,32k+32) -> by in {2k,2k+1}: its 2
    // A-panels (2 MB) stay L2-resident while B streams.
    const int bid = blockIdx.y * 16 + blockIdx.x;
    const int swz = (bid & 7) * 32 + (bid >> 3);
    const int m0 = (swz >> 4) * 256, n0 = (swz & 15) * 256;

    const int r = lane & 15;        // row/col within 16
    const int q = lane >> 4;        // K-quad (16 B) within 64

    // Frag read offsets (swizzled pos independent of mi/ni: (row+16*mi)>>1
    // changes by 8*mi == 0 mod 4 -> mi folds into the immediate offset).
    const int rowA = wm * 128 + r;
    const int aoff = rowA * 64 + ((q + (rowA >> 1)) & 3) * 16;
    const int rowB = wn * 64 + r;
    const int boff = rowB * 64 + ((q + (rowB >> 1)) & 3) * 16;

    // Staging: 1024 16B-chunks per tensor per K-tile, 2 per thread. Linear
    // LDS destination (global_load_lds requirement); global source quad is
    // inverse-swizzled: chunk C -> row C>>2, pos C&3 holds quad (pos-row>>1)&3.
    const int C0 = tid, C1 = tid + 512;
    const int rS0 = C0 >> 2, G0 = ((C0 & 3) - (rS0 >> 1)) & 3;
    const int rS1 = C1 >> 2, G1 = ((C1 & 3) - (rS1 >> 1)) & 3;
    const gptr1_t pA0 = (gptr1_t)(qA + (size_t)(m0 + rS0) * NROW + G0 * 16);
    const gptr1_t pA1 = (gptr1_t)(qA + (size_t)(m0 + rS1) * NROW + G1 * 16);
    const gptr1_t pB0 = (gptr1_t)(qBT + (size_t)(n0 + rS0) * NROW + G0 * 16);
    const gptr1_t pB1 = (gptr1_t)(qBT + (size_t)(n0 + rS1) * NROW + G1 * 16);
    int8_t* sAf = &sA[0][0];
    int8_t* sBf = &sB[0][0];
    const int d0 = C0 * 16, d1 = C1 * 16;

    int32x4 acc[8][4];
#pragma unroll
    for (int mi = 0; mi < 8; ++mi)
#pragma unroll
        for (int ni = 0; ni < 4; ++ni) acc[mi][ni] = (int32x4)(0);

    Frags F0, F1;

    // Prologue: stage tiles 0,1,2 into slots 0,1,2 (12 loads/thread);
    // vmcnt(8) retires tile 0 -> barrier -> read tile 0 frags into F0;
    // vmcnt(4) retires tile 1 (read during window 0) -> barrier.
#pragma unroll
    for (int t = 0; t < 3; ++t) {
        const int kb = t * 64, sb = t * 16384;
        __builtin_amdgcn_global_load_lds(pA0 + kb, (lptr3_t)(sAf + sb + d0), 16, 0, 0);
        __builtin_amdgcn_global_load_lds(pA1 + kb, (lptr3_t)(sAf + sb + d1), 16, 0, 0);
        __builtin_amdgcn_global_load_lds(pB0 + kb, (lptr3_t)(sBf + sb + d0), 16, 0, 0);
        __builtin_amdgcn_global_load_lds(pB1 + kb, (lptr3_t)(sBf + sb + d1), 16, 0, 0);
    }
    asm volatile("s_waitcnt vmcnt(8)" ::: "memory");
    __builtin_amdgcn_sched_barrier(0);
    __builtin_amdgcn_s_barrier();
    read_frags(F0, sAf, sBf, aoff, boff);
    asm volatile("s_waitcnt vmcnt(4)" ::: "memory");
    __builtin_amdgcn_sched_barrier(0);
    __builtin_amdgcn_s_barrier();

    // Steady windows 0..59 (pairs): window t MFMAs tile t, reads tile t+1
    // from slot (t+1)&3, stages tile t+3 into slot (t+3)&3.
#pragma unroll 1
    for (int t = 0; t < 60; t += 2) {
        {
            const int rs = (t + 1) & 3, ss = (t + 3) & 3, kb = (t + 3) * 64;
            window<true, 4>(acc, F0, F1, sAf + rs * 16384, sBf + rs * 16384,
                            aoff, boff, mfma_first, pA0 + kb, pA1 + kb,
                            pB0 + kb, pB1 + kb,
                            (lptr3_t)(sAf + ss * 16384 + d0),
                            (lptr3_t)(sAf + ss * 16384 + d1),
                            (lptr3_t)(sBf + ss * 16384 + d0),
                            (lptr3_t)(sBf + ss * 16384 + d1));
        }
        {
            const int rs = (t + 2) & 3, ss = (t + 4) & 3, kb = (t + 4) * 64;
            window<true, 4>(acc, F1, F0, sAf + rs * 16384, sBf + rs * 16384,
                            aoff, boff, mfma_first, pA0 + kb, pA1 + kb,
                            pB0 + kb, pB1 + kb,
                            (lptr3_t)(sAf + ss * 16384 + d0),
                            (lptr3_t)(sAf + ss * 16384 + d1),
                            (lptr3_t)(sBf + ss * 16384 + d0),
                            (lptr3_t)(sBf + ss * 16384 + d1));
        }
    }
    // Window 60: stage tile 63 (last), read tile 61. vmcnt(4) retires 62.
    window<true, 4>(acc, F0, F1, sAf + ((61) & 3) * 16384,
                    sBf + ((61) & 3) * 16384, aoff, boff, mfma_first,
                    pA0 + 63 * 64, pA1 + 63 * 64, pB0 + 63 * 64, pB1 + 63 * 64,
                    (lptr3_t)(sAf + 3 * 16384 + d0),
                    (lptr3_t)(sAf + 3 * 16384 + d1),
                    (lptr3_t)(sBf + 3 * 16384 + d0),
                    (lptr3_t)(sBf + 3 * 16384 + d1));
    // Window 61: read tile 62; drain tile 63's loads (issued 1 window ago).
    window<false, 0>(acc, F1, F0, sAf + ((62) & 3) * 16384,
                     sBf + ((62) & 3) * 16384, aoff, boff, mfma_first, pA0,
                     pA1, pB0, pB1, (lptr3_t)(sAf + d0), (lptr3_t)(sAf + d1),
                     (lptr3_t)(sBf + d0), (lptr3_t)(sBf + d1));
    // Window 62: read tile 63.
    window<false, -1>(acc, F0, F1, sAf + ((63) & 3) * 16384,
                      sBf + ((63) & 3) * 16384, aoff, boff, mfma_first, pA0,
                      pA1, pB0, pB1, (lptr3_t)(sAf + d0), (lptr3_t)(sAf + d1),
                      (lptr3_t)(sBf + d0), (lptr3_t)(sBf + d1));
    // Window 63: compute-only.
    mfma_all(acc, F1);

    // Epilogue: dequant + store. C/D layout: col = lane&15, row = (lane>>4)*4+reg
    const float ls = 127.0f / fmaxf(__uint_as_float(amax[0]), 1e-12f);
    const float rs = 127.0f / fmaxf(__uint_as_float(amax[1]), 1e-12f);
    const float inv = 1.0f / (ls * rs);
#pragma unroll
    for (int mi = 0; mi < 8; ++mi)
#pragma unroll
        for (int ni = 0; ni < 4; ++ni)
#pragma unroll
            for (int reg = 0; reg < 4; ++reg) {
                const int row = m0 + wm * 128 + mi * 16 + q * 4 + reg;
                const int col = n0 + wn * 64 + ni * 16 + r;
                out[(size_t)row * NROW + col] = (float)acc[mi][ni][reg] * inv;
            }
}

extern "C" void kernel_launch(void* const* d_in, const int* in_sizes, int n_in,
                              void* d_out, int out_size, void* d_ws,
                              size_t ws_size, hipStream_t stream) {
    const float* lhs = (const float*)d_in[0];
    const float* rhs = (const float*)d_in[1];
    float* out = (float*)d_out;

    int8_t* qA = (int8_t*)d_ws;
    int8_t* qBT = qA + (size_t)16 * 1024 * 1024;
    unsigned* amax = (unsigned*)(qBT + (size_t)16 * 1024 * 1024);

    hipMemsetAsync(amax, 0, 8, stream);
    absmax_both_kernel<<<2048, 256, 0, stream>>>(lhs, rhs, amax);
    quant_kernel<<<16384 + 4096, 256, 0, stream>>>(lhs, rhs, qA, qBT, amax);
    gemm_i8_kernel<<<dim3(16, 16), 512, 0, stream>>>(qA, qBT, out, amax);
}

// Round 5
// 439.478 us; speedup vs baseline: 1.8113x; 1.8113x over previous
//
#include <hip/hip_runtime.h>
#include <stdint.h>

// out = dequant( int8(lhs*ls) @ int8(rhs*rs) ) / (ls*rs), 4096^3, fp32 in/out.
// ls = 127 / max(amax|lhs|, 1e-12). Int core is bit-exact vs numpy (RNE quant).
//
// Workspace: [0,16Mi) qA int8 MxK ; [16Mi,32Mi) qBT int8 NxK ; then 2x u32 amax bits.
//
// GEMM v5 (resubmit -- round 4 died to container infra before any dispatch).
// FAT-WAVE geometry. 256x256 tile, 4 waves (256 thr), wave-tile 128x128
// (acc 8x8 frags = 256 regs, 1 wave/SIMD, full 512-reg unified file).
// Rationale: per-CU LDS frag-read bytes per K-tile = sum over waves of
// (Wm+Wn)*BK. 8 thin waves (128x64) = 96 KB -> LDS pipe (~1450 cyc) >= MFMA
// pipe (1306 cyc) -> serial-phase ceiling ~45% (v1-v3 all hit 28-37%).
// 4 fat waves (128x128) = 64 KB -> LDS ~1050 cyc < MFMA 1306 cyc: MFMA-
// dominant. Latency hiding at 1 wave/SIMD via register F-double-buffer
// (window t: MFMA tile t from regs, then ds-read tile t+1 frags -- they get
// a full window + barrier to land), ring-3 LDS (96 KiB), counted vmcnt(8)
// (never drained in steady state), ONE barrier per window, no sched fences
// between reads and MFMAs (compiler interleaves freely; lgkm waits sink to
// next window). Frag reads bank-conflict-free via v2's verified pre-swizzled
// staging source: LDS row (64 B = 4 quads) position p holds global quad
// (p - (row>>1)) & 3; read pos (q + (row>>1)) & 3.

#define NROW 4096
#define NELEM (4096 * 4096)

typedef __attribute__((ext_vector_type(4))) int int32x4;
typedef const __attribute__((address_space(1))) int8_t* gptr1_t;
typedef __attribute__((address_space(3))) int8_t* lptr3_t;

__global__ void absmax_both_kernel(const float* __restrict__ lhs,
                                   const float* __restrict__ rhs,
                                   unsigned* __restrict__ amax) {
    __shared__ float red[4];
    const int t = blockIdx.x & 1;
    const float4* x4 = (const float4*)(t ? rhs : lhs);
    const int bid = blockIdx.x >> 1;
    const int stride = (gridDim.x >> 1) * blockDim.x;  // 262144
    int i = bid * blockDim.x + threadIdx.x;
    float m0 = 0.0f, m1 = 0.0f, m2 = 0.0f, m3 = 0.0f;
    for (; i + 3 * stride < NELEM / 4; i += 4 * stride) {
        float4 a = x4[i];
        float4 b = x4[i + stride];
        float4 c = x4[i + 2 * stride];
        float4 d = x4[i + 3 * stride];
        m0 = fmaxf(m0, fmaxf(fmaxf(fabsf(a.x), fabsf(a.y)),
                             fmaxf(fabsf(a.z), fabsf(a.w))));
        m1 = fmaxf(m1, fmaxf(fmaxf(fabsf(b.x), fabsf(b.y)),
                             fmaxf(fabsf(b.z), fabsf(b.w))));
        m2 = fmaxf(m2, fmaxf(fmaxf(fabsf(c.x), fabsf(c.y)),
                             fmaxf(fabsf(c.z), fabsf(c.w))));
        m3 = fmaxf(m3, fmaxf(fmaxf(fabsf(d.x), fabsf(d.y)),
                             fmaxf(fabsf(d.z), fabsf(d.w))));
    }
    for (; i < NELEM / 4; i += stride) {
        float4 a = x4[i];
        m0 = fmaxf(m0, fmaxf(fmaxf(fabsf(a.x), fabsf(a.y)),
                             fmaxf(fabsf(a.z), fabsf(a.w))));
    }
    float m = fmaxf(fmaxf(m0, m1), fmaxf(m2, m3));
    for (int off = 32; off > 0; off >>= 1)
        m = fmaxf(m, __shfl_down(m, off, 64));
    const int lane = threadIdx.x & 63, wave = threadIdx.x >> 6;
    if (lane == 0) red[wave] = m;
    __syncthreads();
    if (threadIdx.x == 0) {
        float b = fmaxf(fmaxf(red[0], red[1]), fmaxf(red[2], red[3]));
        atomicMax(amax + t, __float_as_uint(b));  // |x|>=0: bits monotone as uint
    }
}

__device__ __forceinline__ int q8(float v, float s) {
    int r = __float2int_rn(v * s);  // RNE, matches jnp.round
    r = r < -127 ? -127 : r;
    r = r > 127 ? 127 : r;
    return r;
}

__global__ void quant_kernel(const float* __restrict__ lhs,
                             const float* __restrict__ rhs,
                             int8_t* __restrict__ qA, int8_t* __restrict__ qT,
                             const unsigned* __restrict__ amax) {
    __shared__ int8_t sm[64][68];
    if (blockIdx.x < 16384) {
        const float s = 127.0f / fmaxf(__uint_as_float(amax[0]), 1e-12f);
        const int i = blockIdx.x * blockDim.x + threadIdx.x;
        float4 v = ((const float4*)lhs)[i];
        int b0 = q8(v.x, s), b1 = q8(v.y, s), b2 = q8(v.z, s), b3 = q8(v.w, s);
        ((int*)qA)[i] = (b0 & 0xff) | ((b1 & 0xff) << 8) | ((b2 & 0xff) << 16)
                      | ((b3 & 0xff) << 24);
    } else {
        const float s = 127.0f / fmaxf(__uint_as_float(amax[1]), 1e-12f);
        const int b = blockIdx.x - 16384;
        const int n0 = (b & 63) * 64, k0 = (b >> 6) * 64;
        const int rl = threadIdx.x >> 4;   // k row within 16-row slab
        const int nq = threadIdx.x & 15;   // float4 column
        for (int r = 0; r < 4; ++r) {
            const int kl = r * 16 + rl;
            float4 v = *(const float4*)(rhs + (size_t)(k0 + kl) * NROW + n0 + nq * 4);
            sm[nq * 4 + 0][kl] = (int8_t)q8(v.x, s);
            sm[nq * 4 + 1][kl] = (int8_t)q8(v.y, s);
            sm[nq * 4 + 2][kl] = (int8_t)q8(v.z, s);
            sm[nq * 4 + 3][kl] = (int8_t)q8(v.w, s);
        }
        __syncthreads();
        const int nl = threadIdx.x >> 2;
        const int kq = threadIdx.x & 3;
        int4 w;
        w.x = *(const int*)&sm[nl][kq * 16 + 0];
        w.y = *(const int*)&sm[nl][kq * 16 + 4];
        w.z = *(const int*)&sm[nl][kq * 16 + 8];
        w.w = *(const int*)&sm[nl][kq * 16 + 12];
        *(int4*)(qT + (size_t)(n0 + nl) * NROW + k0 + kq * 16) = w;
    }
}

__device__ __forceinline__ void mfma_all(int32x4 (&acc)[8][8],
                                         const int32x4 (&fa)[8],
                                         const int32x4 (&fb)[8]) {
#pragma unroll
    for (int mi = 0; mi < 8; ++mi)
#pragma unroll
        for (int ni = 0; ni < 8; ++ni)
            acc[mi][ni] = __builtin_amdgcn_mfma_i32_16x16x64_i8(
                fa[mi], fb[ni], acc[mi][ni], 0, 0, 0);
}

__device__ __forceinline__ void read_frags(int32x4 (&fa)[8], int32x4 (&fb)[8],
                                           const int8_t* a, const int8_t* b,
                                           int aoff, int boff) {
#pragma unroll
    for (int mi = 0; mi < 8; ++mi)
        fa[mi] = *(const int32x4*)(a + aoff + mi * 1024);
#pragma unroll
    for (int ni = 0; ni < 8; ++ni)
        fb[ni] = *(const int32x4*)(b + boff + ni * 1024);
}

// 256x256 tile, 4 waves (2Mx2N of 128x128), BK=64, ring-3 LDS, reg F-dbuf.
// Window w: [stage tile w+2 -> slot (w+2)%3 ; vmcnt(8) retires tile w+1 ;
// s_barrier ; MFMA tile w from F regs ; ds-read tile w+1 frags -> other F].
// Slot (w+2)%3's previous readers finished before their window-(w-1) MFMA
// (lgkm-waited), >=1300 cyc + HBM latency before the overwrite data lands.
// vmcnt(8) is per-wave but precedes the barrier, so every wave's tile-(w+1)
// writes have landed before any wave's post-barrier reads.
__global__ __launch_bounds__(256, 1) void gemm_i8_kernel(
    const int8_t* __restrict__ qA, const int8_t* __restrict__ qBT,
    float* __restrict__ out, const unsigned* __restrict__ amax) {
    __shared__ __align__(16) int8_t sA[3][256 * 64];
    __shared__ __align__(16) int8_t sB[3][256 * 64];

    const int tid = threadIdx.x;
    const int lane = tid & 63;
    const int wave = tid >> 6;      // 0..3
    const int wm = wave >> 1;       // 0..1 : 128-row sub-tile
    const int wn = wave & 1;        // 0..1 : 128-col sub-tile

    // XCD-aware bijective swizzle (grid 256, 256%8==0): XCD k gets swz ids
    // [32k,32k+32) -> 2 contiguous M-rows: A-panels L2-resident per XCD.
    const int bid = blockIdx.y * 16 + blockIdx.x;
    const int swz = (bid & 7) * 32 + (bid >> 3);
    const int m0 = (swz >> 4) * 256, n0 = (swz & 15) * 256;

    const int r = lane & 15;        // row/col within 16
    const int q = lane >> 4;        // K-quad (16 B) within 64

    // Frag read offsets. Swizzled pos = (q + (row>>1)) & 3 is invariant
    // across mi/ni (row changes by 16 -> row>>1 by 8 == 0 mod 4), so the
    // mi/ni step folds into the ds_read immediate offset (+1024 per tile).
    const int rowA = wm * 128 + r;
    const int aoff = rowA * 64 + ((q + (rowA >> 1)) & 3) * 16;
    const int rowB = wn * 128 + r;
    const int boff = rowB * 64 + ((q + (rowB >> 1)) & 3) * 16;

    // Staging: 1024 16B-chunks per tensor per K-tile, 4 per thread. Linear
    // LDS destination (global_load_lds requirement); global source quad is
    // inverse-swizzled: chunk c -> row c>>2, pos c&3 holds quad (pos-row>>1)&3.
    gptr1_t pA[4], pB[4];
#pragma unroll
    for (int j = 0; j < 4; ++j) {
        const int c = tid + j * 256;
        const int row = c >> 2;
        const int G = ((c & 3) - (row >> 1)) & 3;
        pA[j] = (gptr1_t)(qA + (size_t)(m0 + row) * NROW + G * 16);
        pB[j] = (gptr1_t)(qBT + (size_t)(n0 + row) * NROW + G * 16);
    }
    int8_t* sAf = &sA[0][0];
    int8_t* sBf = &sB[0][0];
    const int dst0 = tid * 16;

    auto stage = [&](int slot, int kb) {
#pragma unroll
        for (int j = 0; j < 4; ++j) {
            __builtin_amdgcn_global_load_lds(
                pA[j] + kb, (lptr3_t)(sAf + slot * 16384 + dst0 + j * 4096),
                16, 0, 0);
            __builtin_amdgcn_global_load_lds(
                pB[j] + kb, (lptr3_t)(sBf + slot * 16384 + dst0 + j * 4096),
                16, 0, 0);
        }
    };

    int32x4 acc[8][8];
#pragma unroll
    for (int mi = 0; mi < 8; ++mi)
#pragma unroll
        for (int ni = 0; ni < 8; ++ni) acc[mi][ni] = (int32x4)(0);

    int32x4 fa0[8], fb0[8], fa1[8], fb1[8];

    // Prologue: stage tiles 0,1 into slots 0,1; retire tile 0 (keep tile 1's
    // 8 loads in flight across the barrier); read tile 0 frags into F0.
    stage(0, 0);
    stage(1, 64);
    asm volatile("s_waitcnt vmcnt(8)" ::: "memory");
    __builtin_amdgcn_s_barrier();
    asm volatile("" ::: "memory");
    read_frags(fa0, fb0, sAf, sBf, aoff, boff);

    int rs = 1, ss = 2;  // window w: read slot (w+1)%3, stage slot (w+2)%3
#pragma unroll 1
    for (int w = 0; w < 62; w += 2) {
        // window w (even): MFMA F0, read F1
        stage(ss, (w + 2) * 64);
        asm volatile("s_waitcnt vmcnt(8)" ::: "memory");
        __builtin_amdgcn_s_barrier();
        asm volatile("" ::: "memory");
        mfma_all(acc, fa0, fb0);
        read_frags(fa1, fb1, sAf + rs * 16384, sBf + rs * 16384, aoff, boff);
        rs = (rs == 2) ? 0 : rs + 1;
        ss = (ss == 2) ? 0 : ss + 1;
        // window w+1 (odd): MFMA F1, read F0
        stage(ss, (w + 3) * 64);
        asm volatile("s_waitcnt vmcnt(8)" ::: "memory");
        __builtin_amdgcn_s_barrier();
        asm volatile("" ::: "memory");
        mfma_all(acc, fa1, fb1);
        read_frags(fa0, fb0, sAf + rs * 16384, sBf + rs * 16384, aoff, boff);
        rs = (rs == 2) ? 0 : rs + 1;
        ss = (ss == 2) ? 0 : ss + 1;
    }
    // Window 62 (even): no stage; drain tile 63's loads; MFMA tile 62 (F0),
    // read tile 63 (slot rs) into F1.
    asm volatile("s_waitcnt vmcnt(0)" ::: "memory");
    __builtin_amdgcn_s_barrier();
    asm volatile("" ::: "memory");
    mfma_all(acc, fa0, fb0);
    read_frags(fa1, fb1, sAf + rs * 16384, sBf + rs * 16384, aoff, boff);
    // Window 63: compute-only.
    mfma_all(acc, fa1, fb1);

    // Epilogue: dequant + store. C/D layout: col = lane&15, row = (lane>>4)*4+reg
    const float ls = 127.0f / fmaxf(__uint_as_float(amax[0]), 1e-12f);
    const float rrs = 127.0f / fmaxf(__uint_as_float(amax[1]), 1e-12f);
    const float inv = 1.0f / (ls * rrs);
#pragma unroll
    for (int mi = 0; mi < 8; ++mi)
#pragma unroll
        for (int ni = 0; ni < 8; ++ni)
#pragma unroll
            for (int reg = 0; reg < 4; ++reg) {
                const int row = m0 + wm * 128 + mi * 16 + q * 4 + reg;
                const int col = n0 + wn * 128 + ni * 16 + r;
                out[(size_t)row * NROW + col] = (float)acc[mi][ni][reg] * inv;
            }
}

extern "C" void kernel_launch(void* const* d_in, const int* in_sizes, int n_in,
                              void* d_out, int out_size, void* d_ws,
                              size_t ws_size, hipStream_t stream) {
    const float* lhs = (const float*)d_in[0];
    const float* rhs = (const float*)d_in[1];
    float* out = (float*)d_out;

    int8_t* qA = (int8_t*)d_ws;
    int8_t* qBT = qA + (size_t)16 * 1024 * 1024;
    unsigned* amax = (unsigned*)(qBT + (size_t)16 * 1024 * 1024);

    hipMemsetAsync(amax, 0, 8, stream);
    absmax_both_kernel<<<2048, 256, 0, stream>>>(lhs, rhs, amax);
    quant_kernel<<<16384 + 4096, 256, 0, stream>>>(lhs, rhs, qA, qBT, amax);
    gemm_i8_kernel<<<dim3(16, 16), 256, 0, stream>>>(qA, qBT, out, amax);
}

// Round 6
// 437.766 us; speedup vs baseline: 1.8184x; 1.0039x over previous
//
#include <hip/hip_runtime.h>
#include <stdint.h>

// out = dequant( int8(lhs*ls) @ int8(rhs*rs) ) / (ls*rs), 4096^3, fp32 in/out.
// ls = 127 / max(amax|lhs|, 1e-12). Int core is bit-exact vs numpy (RNE quant).
//
// Workspace: [0,16Mi) qA int8 MxK ; [16Mi,32Mi) qBT int8 NxK ; then 2x u32 amax bits.
//
// GEMM v5 (resubmit -- round 4 died to container infra before any dispatch).
// FAT-WAVE geometry. 256x256 tile, 4 waves (256 thr), wave-tile 128x128
// (acc 8x8 frags = 256 regs, 1 wave/SIMD, full 512-reg unified file).
// Rationale: per-CU LDS frag-read bytes per K-tile = sum over waves of
// (Wm+Wn)*BK. 8 thin waves (128x64) = 96 KB -> LDS pipe (~1450 cyc) >= MFMA
// pipe (1306 cyc) -> serial-phase ceiling ~45% (v1-v3 all hit 28-37%).
// 4 fat waves (128x128) = 64 KB -> LDS ~1050 cyc < MFMA 1306 cyc: MFMA-
// dominant. Latency hiding at 1 wave/SIMD via register F-double-buffer
// (window t: MFMA tile t from regs, then ds-read tile t+1 frags -- they get
// a full window + barrier to land), ring-3 LDS (96 KiB), counted vmcnt(8)
// (never drained in steady state), ONE barrier per window, no sched fences
// between reads and MFMAs (compiler interleaves freely; lgkm waits sink to
// next window). Frag reads bank-conflict-free via v2's verified pre-swizzled
// staging source: LDS row (64 B = 4 quads) position p holds global quad
// (p - (row>>1)) & 3; read pos (q + (row>>1)) & 3.

#define NROW 4096
#define NELEM (4096 * 4096)

typedef __attribute__((ext_vector_type(4))) int int32x4;
typedef const __attribute__((address_space(1))) int8_t* gptr1_t;
typedef __attribute__((address_space(3))) int8_t* lptr3_t;

__global__ void absmax_both_kernel(const float* __restrict__ lhs,
                                   const float* __restrict__ rhs,
                                   unsigned* __restrict__ amax) {
    __shared__ float red[4];
    const int t = blockIdx.x & 1;
    const float4* x4 = (const float4*)(t ? rhs : lhs);
    const int bid = blockIdx.x >> 1;
    const int stride = (gridDim.x >> 1) * blockDim.x;  // 262144
    int i = bid * blockDim.x + threadIdx.x;
    float m0 = 0.0f, m1 = 0.0f, m2 = 0.0f, m3 = 0.0f;
    for (; i + 3 * stride < NELEM / 4; i += 4 * stride) {
        float4 a = x4[i];
        float4 b = x4[i + stride];
        float4 c = x4[i + 2 * stride];
        float4 d = x4[i + 3 * stride];
        m0 = fmaxf(m0, fmaxf(fmaxf(fabsf(a.x), fabsf(a.y)),
                             fmaxf(fabsf(a.z), fabsf(a.w))));
        m1 = fmaxf(m1, fmaxf(fmaxf(fabsf(b.x), fabsf(b.y)),
                             fmaxf(fabsf(b.z), fabsf(b.w))));
        m2 = fmaxf(m2, fmaxf(fmaxf(fabsf(c.x), fabsf(c.y)),
                             fmaxf(fabsf(c.z), fabsf(c.w))));
        m3 = fmaxf(m3, fmaxf(fmaxf(fabsf(d.x), fabsf(d.y)),
                             fmaxf(fabsf(d.z), fabsf(d.w))));
    }
    for (; i < NELEM / 4; i += stride) {
        float4 a = x4[i];
        m0 = fmaxf(m0, fmaxf(fmaxf(fabsf(a.x), fabsf(a.y)),
                             fmaxf(fabsf(a.z), fabsf(a.w))));
    }
    float m = fmaxf(fmaxf(m0, m1), fmaxf(m2, m3));
    for (int off = 32; off > 0; off >>= 1)
        m = fmaxf(m, __shfl_down(m, off, 64));
    const int lane = threadIdx.x & 63, wave = threadIdx.x >> 6;
    if (lane == 0) red[wave] = m;
    __syncthreads();
    if (threadIdx.x == 0) {
        float b = fmaxf(fmaxf(red[0], red[1]), fmaxf(red[2], red[3]));
        atomicMax(amax + t, __float_as_uint(b));  // |x|>=0: bits monotone as uint
    }
}

__device__ __forceinline__ int q8(float v, float s) {
    int r = __float2int_rn(v * s);  // RNE, matches jnp.round
    r = r < -127 ? -127 : r;
    r = r > 127 ? 127 : r;
    return r;
}

__global__ void quant_kernel(const float* __restrict__ lhs,
                             const float* __restrict__ rhs,
                             int8_t* __restrict__ qA, int8_t* __restrict__ qT,
                             const unsigned* __restrict__ amax) {
    __shared__ int8_t sm[64][68];
    if (blockIdx.x < 16384) {
        const float s = 127.0f / fmaxf(__uint_as_float(amax[0]), 1e-12f);
        const int i = blockIdx.x * blockDim.x + threadIdx.x;
        float4 v = ((const float4*)lhs)[i];
        int b0 = q8(v.x, s), b1 = q8(v.y, s), b2 = q8(v.z, s), b3 = q8(v.w, s);
        ((int*)qA)[i] = (b0 & 0xff) | ((b1 & 0xff) << 8) | ((b2 & 0xff) << 16)
                      | ((b3 & 0xff) << 24);
    } else {
        const float s = 127.0f / fmaxf(__uint_as_float(amax[1]), 1e-12f);
        const int b = blockIdx.x - 16384;
        const int n0 = (b & 63) * 64, k0 = (b >> 6) * 64;
        const int rl = threadIdx.x >> 4;   // k row within 16-row slab
        const int nq = threadIdx.x & 15;   // float4 column
        for (int r = 0; r < 4; ++r) {
            const int kl = r * 16 + rl;
            float4 v = *(const float4*)(rhs + (size_t)(k0 + kl) * NROW + n0 + nq * 4);
            sm[nq * 4 + 0][kl] = (int8_t)q8(v.x, s);
            sm[nq * 4 + 1][kl] = (int8_t)q8(v.y, s);
            sm[nq * 4 + 2][kl] = (int8_t)q8(v.z, s);
            sm[nq * 4 + 3][kl] = (int8_t)q8(v.w, s);
        }
        __syncthreads();
        const int nl = threadIdx.x >> 2;
        const int kq = threadIdx.x & 3;
        int4 w;
        w.x = *(const int*)&sm[nl][kq * 16 + 0];
        w.y = *(const int*)&sm[nl][kq * 16 + 4];
        w.z = *(const int*)&sm[nl][kq * 16 + 8];
        w.w = *(const int*)&sm[nl][kq * 16 + 12];
        *(int4*)(qT + (size_t)(n0 + nl) * NROW + k0 + kq * 16) = w;
    }
}

__device__ __forceinline__ void mfma_all(int32x4 (&acc)[8][8],
                                         const int32x4 (&fa)[8],
                                         const int32x4 (&fb)[8]) {
#pragma unroll
    for (int mi = 0; mi < 8; ++mi)
#pragma unroll
        for (int ni = 0; ni < 8; ++ni)
            acc[mi][ni] = __builtin_amdgcn_mfma_i32_16x16x64_i8(
                fa[mi], fb[ni], acc[mi][ni], 0, 0, 0);
}

__device__ __forceinline__ void read_frags(int32x4 (&fa)[8], int32x4 (&fb)[8],
                                           const int8_t* a, const int8_t* b,
                                           int aoff, int boff) {
#pragma unroll
    for (int mi = 0; mi < 8; ++mi)
        fa[mi] = *(const int32x4*)(a + aoff + mi * 1024);
#pragma unroll
    for (int ni = 0; ni < 8; ++ni)
        fb[ni] = *(const int32x4*)(b + boff + ni * 1024);
}

// 256x256 tile, 4 waves (2Mx2N of 128x128), BK=64, ring-3 LDS, reg F-dbuf.
// Window w: [stage tile w+2 -> slot (w+2)%3 ; vmcnt(8) retires tile w+1 ;
// s_barrier ; MFMA tile w from F regs ; ds-read tile w+1 frags -> other F].
// Slot (w+2)%3's previous readers finished before their window-(w-1) MFMA
// (lgkm-waited), >=1300 cyc + HBM latency before the overwrite data lands.
// vmcnt(8) is per-wave but precedes the barrier, so every wave's tile-(w+1)
// writes have landed before any wave's post-barrier reads.
__global__ __launch_bounds__(256, 1) void gemm_i8_kernel(
    const int8_t* __restrict__ qA, const int8_t* __restrict__ qBT,
    float* __restrict__ out, const unsigned* __restrict__ amax) {
    __shared__ __align__(16) int8_t sA[3][256 * 64];
    __shared__ __align__(16) int8_t sB[3][256 * 64];

    const int tid = threadIdx.x;
    const int lane = tid & 63;
    const int wave = tid >> 6;      // 0..3
    const int wm = wave >> 1;       // 0..1 : 128-row sub-tile
    const int wn = wave & 1;        // 0..1 : 128-col sub-tile

    // XCD-aware bijective swizzle (grid 256, 256%8==0): XCD k gets swz ids
    // [32k,32k+32) -> 2 contiguous M-rows: A-panels L2-resident per XCD.
    const int bid = blockIdx.y * 16 + blockIdx.x;
    const int swz = (bid & 7) * 32 + (bid >> 3);
    const int m0 = (swz >> 4) * 256, n0 = (swz & 15) * 256;

    const int r = lane & 15;        // row/col within 16
    const int q = lane >> 4;        // K-quad (16 B) within 64

    // Frag read offsets. Swizzled pos = (q + (row>>1)) & 3 is invariant
    // across mi/ni (row changes by 16 -> row>>1 by 8 == 0 mod 4), so the
    // mi/ni step folds into the ds_read immediate offset (+1024 per tile).
    const int rowA = wm * 128 + r;
    const int aoff = rowA * 64 + ((q + (rowA >> 1)) & 3) * 16;
    const int rowB = wn * 128 + r;
    const int boff = rowB * 64 + ((q + (rowB >> 1)) & 3) * 16;

    // Staging: 1024 16B-chunks per tensor per K-tile, 4 per thread. Linear
    // LDS destination (global_load_lds requirement); global source quad is
    // inverse-swizzled: chunk c -> row c>>2, pos c&3 holds quad (pos-row>>1)&3.
    gptr1_t pA[4], pB[4];
#pragma unroll
    for (int j = 0; j < 4; ++j) {
        const int c = tid + j * 256;
        const int row = c >> 2;
        const int G = ((c & 3) - (row >> 1)) & 3;
        pA[j] = (gptr1_t)(qA + (size_t)(m0 + row) * NROW + G * 16);
        pB[j] = (gptr1_t)(qBT + (size_t)(n0 + row) * NROW + G * 16);
    }
    int8_t* sAf = &sA[0][0];
    int8_t* sBf = &sB[0][0];
    const int dst0 = tid * 16;

    auto stage = [&](int slot, int kb) {
#pragma unroll
        for (int j = 0; j < 4; ++j) {
            __builtin_amdgcn_global_load_lds(
                pA[j] + kb, (lptr3_t)(sAf + slot * 16384 + dst0 + j * 4096),
                16, 0, 0);
            __builtin_amdgcn_global_load_lds(
                pB[j] + kb, (lptr3_t)(sBf + slot * 16384 + dst0 + j * 4096),
                16, 0, 0);
        }
    };

    int32x4 acc[8][8];
#pragma unroll
    for (int mi = 0; mi < 8; ++mi)
#pragma unroll
        for (int ni = 0; ni < 8; ++ni) acc[mi][ni] = (int32x4)(0);

    int32x4 fa0[8], fb0[8], fa1[8], fb1[8];

    // Prologue: stage tiles 0,1 into slots 0,1; retire tile 0 (keep tile 1's
    // 8 loads in flight across the barrier); read tile 0 frags into F0.
    stage(0, 0);
    stage(1, 64);
    asm volatile("s_waitcnt vmcnt(8)" ::: "memory");
    __builtin_amdgcn_s_barrier();
    asm volatile("" ::: "memory");
    read_frags(fa0, fb0, sAf, sBf, aoff, boff);

    int rs = 1, ss = 2;  // window w: read slot (w+1)%3, stage slot (w+2)%3
#pragma unroll 1
    for (int w = 0; w < 62; w += 2) {
        // window w (even): MFMA F0, read F1
        stage(ss, (w + 2) * 64);
        asm volatile("s_waitcnt vmcnt(8)" ::: "memory");
        __builtin_amdgcn_s_barrier();
        asm volatile("" ::: "memory");
        mfma_all(acc, fa0, fb0);
        read_frags(fa1, fb1, sAf + rs * 16384, sBf + rs * 16384, aoff, boff);
        rs = (rs == 2) ? 0 : rs + 1;
        ss = (ss == 2) ? 0 : ss + 1;
        // window w+1 (odd): MFMA F1, read F0
        stage(ss, (w + 3) * 64);
        asm volatile("s_waitcnt vmcnt(8)" ::: "memory");
        __builtin_amdgcn_s_barrier();
        asm volatile("" ::: "memory");
        mfma_all(acc, fa1, fb1);
        read_frags(fa0, fb0, sAf + rs * 16384, sBf + rs * 16384, aoff, boff);
        rs = (rs == 2) ? 0 : rs + 1;
        ss = (ss == 2) ? 0 : ss + 1;
    }
    // Window 62 (even): no stage; drain tile 63's loads; MFMA tile 62 (F0),
    // read tile 63 (slot rs) into F1.
    asm volatile("s_waitcnt vmcnt(0)" ::: "memory");
    __builtin_amdgcn_s_barrier();
    asm volatile("" ::: "memory");
    mfma_all(acc, fa0, fb0);
    read_frags(fa1, fb1, sAf + rs * 16384, sBf + rs * 16384, aoff, boff);
    // Window 63: compute-only.
    mfma_all(acc, fa1, fb1);

    // Epilogue: dequant + store. C/D layout: col = lane&15, row = (lane>>4)*4+reg
    const float ls = 127.0f / fmaxf(__uint_as_float(amax[0]), 1e-12f);
    const float rrs = 127.0f / fmaxf(__uint_as_float(amax[1]), 1e-12f);
    const float inv = 1.0f / (ls * rrs);
#pragma unroll
    for (int mi = 0; mi < 8; ++mi)
#pragma unroll
        for (int ni = 0; ni < 8; ++ni)
#pragma unroll
            for (int reg = 0; reg < 4; ++reg) {
                const int row = m0 + wm * 128 + mi * 16 + q * 4 + reg;
                const int col = n0 + wn * 128 + ni * 16 + r;
                out[(size_t)row * NROW + col] = (float)acc[mi][ni][reg] * inv;
            }
}

extern "C" void kernel_launch(void* const* d_in, const int* in_sizes, int n_in,
                              void* d_out, int out_size, void* d_ws,
                              size_t ws_size, hipStream_t stream) {
    const float* lhs = (const float*)d_in[0];
    const float* rhs = (const float*)d_in[1];
    float* out = (float*)d_out;

    int8_t* qA = (int8_t*)d_ws;
    int8_t* qBT = qA + (size_t)16 * 1024 * 1024;
    unsigned* amax = (unsigned*)(qBT + (size_t)16 * 1024 * 1024);

    hipMemsetAsync(amax, 0, 8, stream);
    absmax_both_kernel<<<2048, 256, 0, stream>>>(lhs, rhs, amax);
    quant_kernel<<<16384 + 4096, 256, 0, stream>>>(lhs, rhs, qA, qBT, amax);
    gemm_i8_kernel<<<dim3(16, 16), 256, 0, stream>>>(qA, qBT, out, amax);
}

// Round 7
// 139.392 us; speedup vs baseline: 5.7108x; 3.1405x over previous
//
#include <hip/hip_runtime.h>
#include <stdint.h>

// out = dequant( int8(lhs*ls) @ int8(rhs*rs) ) / (ls*rs), 4096^3, fp32 in/out.
// ls = 127 / max(amax|lhs|, 1e-12). Int core is bit-exact vs numpy (RNE quant).
//
// Workspace: [0,16Mi) qA int8 MxK ; [16Mi,32Mi) qBT int8 NxK ; then 2x u32 amax bits.
//
// GEMM v6: overhead amortization. 256x256 tile, 8 waves (2Mx4N, 128x64 wave
// tile -- the v2/v3 register shape that verified no-spill at 112-128 VGPRs),
// BK=128 windows (2x the MFMA work per barrier window vs v2/v3; v1-v3 all
// showed ~1.5-2.2k cyc of per-window overhead that is independent of window
// size, and i8's 2xK halves MFMA cycles per window vs bf16 -- so double the
// window). Double-buffered LDS (2 x 32 KiB x 2 tensors = 128 KiB), prefetch
// distance 1: stage tile w+1 at window-w start; vmcnt(0) at window END waits
// on ~3000-cycle-old loads (free -- unlike m97's zero-distance drain). ONE
// barrier per window, 32 windows. Frag reads conflict-free via v1's verified
// 128B-row pre-swizzled staging: LDS row (128 B = 8 quads) position p holds
// global quad (p - row) & 7; frag for global quad g reads pos (g + row) & 7.

#define NROW 4096
#define NELEM (4096 * 4096)

typedef __attribute__((ext_vector_type(4))) int int32x4;
typedef const __attribute__((address_space(1))) int8_t* gptr1_t;
typedef __attribute__((address_space(3))) int8_t* lptr3_t;

__global__ void absmax_both_kernel(const float* __restrict__ lhs,
                                   const float* __restrict__ rhs,
                                   unsigned* __restrict__ amax) {
    __shared__ float red[4];
    const int t = blockIdx.x & 1;
    const float4* x4 = (const float4*)(t ? rhs : lhs);
    const int bid = blockIdx.x >> 1;
    const int stride = (gridDim.x >> 1) * blockDim.x;  // 262144
    int i = bid * blockDim.x + threadIdx.x;
    float m0 = 0.0f, m1 = 0.0f, m2 = 0.0f, m3 = 0.0f;
    for (; i + 3 * stride < NELEM / 4; i += 4 * stride) {
        float4 a = x4[i];
        float4 b = x4[i + stride];
        float4 c = x4[i + 2 * stride];
        float4 d = x4[i + 3 * stride];
        m0 = fmaxf(m0, fmaxf(fmaxf(fabsf(a.x), fabsf(a.y)),
                             fmaxf(fabsf(a.z), fabsf(a.w))));
        m1 = fmaxf(m1, fmaxf(fmaxf(fabsf(b.x), fabsf(b.y)),
                             fmaxf(fabsf(b.z), fabsf(b.w))));
        m2 = fmaxf(m2, fmaxf(fmaxf(fabsf(c.x), fabsf(c.y)),
                             fmaxf(fabsf(c.z), fabsf(c.w))));
        m3 = fmaxf(m3, fmaxf(fmaxf(fabsf(d.x), fabsf(d.y)),
                             fmaxf(fabsf(d.z), fabsf(d.w))));
    }
    for (; i < NELEM / 4; i += stride) {
        float4 a = x4[i];
        m0 = fmaxf(m0, fmaxf(fmaxf(fabsf(a.x), fabsf(a.y)),
                             fmaxf(fabsf(a.z), fabsf(a.w))));
    }
    float m = fmaxf(fmaxf(m0, m1), fmaxf(m2, m3));
    for (int off = 32; off > 0; off >>= 1)
        m = fmaxf(m, __shfl_down(m, off, 64));
    const int lane = threadIdx.x & 63, wave = threadIdx.x >> 6;
    if (lane == 0) red[wave] = m;
    __syncthreads();
    if (threadIdx.x == 0) {
        float b = fmaxf(fmaxf(red[0], red[1]), fmaxf(red[2], red[3]));
        atomicMax(amax + t, __float_as_uint(b));  // |x|>=0: bits monotone as uint
    }
}

__device__ __forceinline__ int q8(float v, float s) {
    int r = __float2int_rn(v * s);  // RNE, matches jnp.round
    r = r < -127 ? -127 : r;
    r = r > 127 ? 127 : r;
    return r;
}

__global__ void quant_kernel(const float* __restrict__ lhs,
                             const float* __restrict__ rhs,
                             int8_t* __restrict__ qA, int8_t* __restrict__ qT,
                             const unsigned* __restrict__ amax) {
    __shared__ int8_t sm[64][68];
    if (blockIdx.x < 16384) {
        const float s = 127.0f / fmaxf(__uint_as_float(amax[0]), 1e-12f);
        const int i = blockIdx.x * blockDim.x + threadIdx.x;
        float4 v = ((const float4*)lhs)[i];
        int b0 = q8(v.x, s), b1 = q8(v.y, s), b2 = q8(v.z, s), b3 = q8(v.w, s);
        ((int*)qA)[i] = (b0 & 0xff) | ((b1 & 0xff) << 8) | ((b2 & 0xff) << 16)
                      | ((b3 & 0xff) << 24);
    } else {
        const float s = 127.0f / fmaxf(__uint_as_float(amax[1]), 1e-12f);
        const int b = blockIdx.x - 16384;
        const int n0 = (b & 63) * 64, k0 = (b >> 6) * 64;
        const int rl = threadIdx.x >> 4;   // k row within 16-row slab
        const int nq = threadIdx.x & 15;   // float4 column
        for (int r = 0; r < 4; ++r) {
            const int kl = r * 16 + rl;
            float4 v = *(const float4*)(rhs + (size_t)(k0 + kl) * NROW + n0 + nq * 4);
            sm[nq * 4 + 0][kl] = (int8_t)q8(v.x, s);
            sm[nq * 4 + 1][kl] = (int8_t)q8(v.y, s);
            sm[nq * 4 + 2][kl] = (int8_t)q8(v.z, s);
            sm[nq * 4 + 3][kl] = (int8_t)q8(v.w, s);
        }
        __syncthreads();
        const int nl = threadIdx.x >> 2;
        const int kq = threadIdx.x & 3;
        int4 w;
        w.x = *(const int*)&sm[nl][kq * 16 + 0];
        w.y = *(const int*)&sm[nl][kq * 16 + 4];
        w.z = *(const int*)&sm[nl][kq * 16 + 8];
        w.w = *(const int*)&sm[nl][kq * 16 + 12];
        *(int4*)(qT + (size_t)(n0 + nl) * NROW + k0 + kq * 16) = w;
    }
}

// 256x256 tile, 8 waves (wave-tile 128x64), BK=128, double-buffered LDS.
// Window w: [stage tile w+1 -> slot (w+1)&1 (8 global_load_lds/thread);
// compute slot w&1 (2 kk-slices x {12 ds_read_b128 + 32 MFMA});
// vmcnt(0) (loads are a full window old -- no stall); s_barrier].
// WAR safety: slot (w+1)&1 was last read in window w-1, which ended at a
// barrier; re-stage writes land strictly after that barrier.
__global__ __launch_bounds__(512, 2) void gemm_i8_kernel(
    const int8_t* __restrict__ qA, const int8_t* __restrict__ qBT,
    float* __restrict__ out, const unsigned* __restrict__ amax) {
    __shared__ __align__(16) int8_t sA[2][256 * 128];
    __shared__ __align__(16) int8_t sB[2][256 * 128];

    const int tid = threadIdx.x;
    const int lane = tid & 63;
    const int wave = tid >> 6;      // 0..7
    const int wm = wave >> 2;       // 0..1 : 128-row sub-tile
    const int wn = wave & 3;        // 0..3 : 64-col sub-tile

    // XCD-aware bijective swizzle (grid 256, 256%8==0): XCD k gets swz ids
    // [32k,32k+32) -> 2 contiguous M-rows: A-panels L2-resident per XCD.
    const int bid = blockIdx.y * 16 + blockIdx.x;
    const int swz = (bid & 7) * 32 + (bid >> 3);
    const int m0 = (swz >> 4) * 256, n0 = (swz & 15) * 256;

    const int r = lane & 15;        // row/col within 16
    const int q = lane >> 4;        // K-quad (16 B) within the kk half-row

    // Frag read offsets. Row = 128 B = 8 quads; pos = (g + row) & 7 for
    // global quad g = kk*4 + q. (row + 16*mi) & 7 == row & 7 -> pos invariant
    // across mi/ni; the mi/ni step folds into the ds_read immediate (+2048).
    const int rowA = wm * 128 + r;
    const int aoff0 = rowA * 128 + (((q + rowA) & 7) << 4);
    const int rowB = wn * 64 + r;
    const int boff0 = rowB * 128 + (((q + rowB) & 7) << 4);
    // kk=1 adds 4 to the quad index: (x+4)&7 == x^4 -> +/-64 bytes via XOR.

    // Staging: 2048 16B-chunks per tensor per K-tile (256 rows x 8 quads),
    // 4 per thread. Linear LDS destination (global_load_lds requirement);
    // global source quad inverse-swizzled: chunk c -> row c>>3, pos c&7
    // holds global quad ((c&7) - row) & 7.
    gptr1_t pA[4], pB[4];
#pragma unroll
    for (int j = 0; j < 4; ++j) {
        const int c = tid + j * 512;
        const int row = c >> 3;
        const int G = ((c & 7) - row) & 7;
        pA[j] = (gptr1_t)(qA + (size_t)(m0 + row) * NROW + G * 16);
        pB[j] = (gptr1_t)(qBT + (size_t)(n0 + row) * NROW + G * 16);
    }
    int8_t* sAf = &sA[0][0];
    int8_t* sBf = &sB[0][0];
    const int dst0 = tid * 16;

    auto stage = [&](int slot, int kb) {
#pragma unroll
        for (int j = 0; j < 4; ++j) {
            __builtin_amdgcn_global_load_lds(
                pA[j] + kb, (lptr3_t)(sAf + slot * 32768 + dst0 + j * 8192),
                16, 0, 0);
            __builtin_amdgcn_global_load_lds(
                pB[j] + kb, (lptr3_t)(sBf + slot * 32768 + dst0 + j * 8192),
                16, 0, 0);
        }
    };

    int32x4 acc[8][4];
#pragma unroll
    for (int mi = 0; mi < 8; ++mi)
#pragma unroll
        for (int ni = 0; ni < 4; ++ni) acc[mi][ni] = (int32x4)(0);

    auto compute = [&](const int8_t* a, const int8_t* b) {
#pragma unroll
        for (int kk = 0; kk < 2; ++kk) {
            const int ax = aoff0 ^ (kk ? 64 : 0);
            const int bx = boff0 ^ (kk ? 64 : 0);
            int32x4 af[8], bf[4];
#pragma unroll
            for (int mi = 0; mi < 8; ++mi)
                af[mi] = *(const int32x4*)(a + ax + mi * 2048);
#pragma unroll
            for (int ni = 0; ni < 4; ++ni)
                bf[ni] = *(const int32x4*)(b + bx + ni * 2048);
            __builtin_amdgcn_s_setprio(1);
#pragma unroll
            for (int mi = 0; mi < 8; ++mi)
#pragma unroll
                for (int ni = 0; ni < 4; ++ni)
                    acc[mi][ni] = __builtin_amdgcn_mfma_i32_16x16x64_i8(
                        af[mi], bf[ni], acc[mi][ni], 0, 0, 0);
            __builtin_amdgcn_s_setprio(0);
        }
    };

    // Prologue: stage tile 0 into slot 0; drain; barrier.
    stage(0, 0);
    asm volatile("s_waitcnt vmcnt(0)" ::: "memory");
    __builtin_amdgcn_sched_barrier(0);
    __builtin_amdgcn_s_barrier();
    __builtin_amdgcn_sched_barrier(0);

    // 32 K-tiles of 128. Windows 0..30 stage the next tile; window 31 below.
#pragma unroll 1
    for (int w = 0; w < 31; ++w) {
        stage((w + 1) & 1, (w + 1) * 128);
        compute(sAf + (w & 1) * 32768, sBf + (w & 1) * 32768);
        asm volatile("s_waitcnt vmcnt(0)" ::: "memory");
        __builtin_amdgcn_sched_barrier(0);
        __builtin_amdgcn_s_barrier();
        __builtin_amdgcn_sched_barrier(0);
    }
    compute(sAf + 32768, sBf + 32768);  // tile 31, slot 1

    // Epilogue: dequant + store. C/D layout: col = lane&15, row = (lane>>4)*4+reg
    const float ls = 127.0f / fmaxf(__uint_as_float(amax[0]), 1e-12f);
    const float rs = 127.0f / fmaxf(__uint_as_float(amax[1]), 1e-12f);
    const float inv = 1.0f / (ls * rs);
#pragma unroll
    for (int mi = 0; mi < 8; ++mi)
#pragma unroll
        for (int ni = 0; ni < 4; ++ni)
#pragma unroll
            for (int reg = 0; reg < 4; ++reg) {
                const int row = m0 + wm * 128 + mi * 16 + q * 4 + reg;
                const int col = n0 + wn * 64 + ni * 16 + r;
                out[(size_t)row * NROW + col] = (float)acc[mi][ni][reg] * inv;
            }
}

extern "C" void kernel_launch(void* const* d_in, const int* in_sizes, int n_in,
                              void* d_out, int out_size, void* d_ws,
                              size_t ws_size, hipStream_t stream) {
    const float* lhs = (const float*)d_in[0];
    const float* rhs = (const float*)d_in[1];
    float* out = (float*)d_out;

    int8_t* qA = (int8_t*)d_ws;
    int8_t* qBT = qA + (size_t)16 * 1024 * 1024;
    unsigned* amax = (unsigned*)(qBT + (size_t)16 * 1024 * 1024);

    hipMemsetAsync(amax, 0, 8, stream);
    absmax_both_kernel<<<2048, 256, 0, stream>>>(lhs, rhs, amax);
    quant_kernel<<<16384 + 4096, 256, 0, stream>>>(lhs, rhs, qA, qBT, amax);
    gemm_i8_kernel<<<dim3(16, 16), 512, 0, stream>>>(qA, qBT, out, amax);
}